// Round 4
// baseline (614.149 us; speedup 1.0000x reference)
//
#include <hip/hip_runtime.h>

#define NB 8192
#define NT 1024
#define NH 10

typedef float v2f __attribute__((ext_vector_type(2)));
typedef float v4f __attribute__((ext_vector_type(4)));

__device__ __forceinline__ float rcpf(float x) { return __builtin_amdgcn_rcpf(x); }
__device__ __forceinline__ float sigm(float x) { return rcpf(1.0f + __expf(-x)); }
__device__ __forceinline__ float tanhx(float x) { return 1.0f - 2.0f * rcpf(__expf(2.0f * x) + 1.0f); }

struct W10 { v4f a, b; v2f c; };

__device__ __forceinline__ W10 loadrow(const float* __restrict__ p) {
    W10 w;
    w.a = (v4f){p[0], p[1], p[2], p[3]};
    w.b = (v4f){p[4], p[5], p[6], p[7]};
    w.c = (v2f){p[8], p[9]};
    return w;
}
// single 10-dot: sum(w .* h)
__device__ __forceinline__ float dotW(const W10& w, v4f ha, v4f hb, v2f hc) {
    v4f a = w.a * ha + w.b * hb;
    v2f c = w.c * hc;
    return (a.x + a.y) + (a.z + a.w) + (c.x + c.y);
}
// fused double 10-dot: sum(w1 .* h) + sum(w2 .* g)  (one horizontal sum)
__device__ __forceinline__ float dotWW(const W10& w1, v4f ha, v4f hb, v2f hc,
                                       const W10& w2, v4f ga, v4f gb, v2f gc) {
    v4f a = w1.a * ha + w1.b * hb;
    a = a + w2.a * ga + w2.b * gb;
    v2f c = w1.c * hc + w2.c * gc;
    return (a.x + a.y) + (a.z + a.w) + (c.x + c.y);
}

__global__ __launch_bounds__(256, 2) void gru_fused(
    const float* __restrict__ X,
    const float* __restrict__ Wih0, const float* __restrict__ Whh0,
    const float* __restrict__ bih0, const float* __restrict__ bhh0,
    const float* __restrict__ Wih1, const float* __restrict__ Whh1,
    const float* __restrict__ bih1, const float* __restrict__ bhh1,
    const float* __restrict__ Wfc,  const float* __restrict__ bfc,
    float* __restrict__ out)
{
    // [wave][group(7 incl. idle)][layer][20 floats]: group stride 40 floats
    // -> group bank sets {0-3,8-11,16-19,24-27}: conflict-free b128 reads.
    __shared__ __align__(16) float hls[4][7][2][20];

    const int tid  = threadIdx.x;
    const int lane = tid & 63;
    const int wv   = tid >> 6;
    const int g    = lane / 10;      // 0..3 real rows, 4..6 idle mirrors of group 0
    const int j    = lane - g * 10;  // 0..9

    const bool active = (g < 4);
    const int b = blockIdx.x * 16 + wv * 4 + (active ? g : 0);

    const int r0 = j, r1 = j + 10, r2 = j + 20;

    // ---- per-lane weight rows, packed v4f/v4f/v2f ----
    const W10 whr0 = loadrow(Whh0 + r0 * NH);
    const W10 whz0 = loadrow(Whh0 + r1 * NH);
    const W10 whn0 = loadrow(Whh0 + r2 * NH);
    const W10 wir1 = loadrow(Wih1 + r0 * NH);
    const W10 wiz1 = loadrow(Wih1 + r1 * NH);
    const W10 win1 = loadrow(Wih1 + r2 * NH);
    const W10 whr1 = loadrow(Whh1 + r0 * NH);
    const W10 whz1 = loadrow(Whh1 + r1 * NH);
    const W10 whn1 = loadrow(Whh1 + r2 * NH);
    const v2f wxr = (v2f){Wih0[r0 * 2], Wih0[r0 * 2 + 1]};
    const v2f wxz = (v2f){Wih0[r1 * 2], Wih0[r1 * 2 + 1]};
    const v2f wxn = (v2f){Wih0[r2 * 2], Wih0[r2 * 2 + 1]};

    const float br0  = bih0[r0] + bhh0[r0];
    const float bz0  = bih0[r1] + bhh0[r1];
    const float bxn0 = bih0[r2];
    const float bhn0 = bhh0[r2];
    const float br1  = bih1[r0] + bhh1[r0];
    const float bz1  = bih1[r1] + bhh1[r1];
    const float bxn1 = bih1[r2];
    const float bhn1 = bhh1[r2];

    float* __restrict__ h0s = &hls[wv][g][0][0];
    float* __restrict__ h1s = &hls[wv][g][1][0];

    // replicated h in packed registers (zero initial state)
    v4f h0a = (v4f){0,0,0,0}, h0b = (v4f){0,0,0,0}; v2f h0c = (v2f){0,0};
    v4f h1a = (v4f){0,0,0,0}, h1b = (v4f){0,0,0,0}; v2f h1c = (v2f){0,0};
    float my0 = 0.0f, my1 = 0.0f;

    const v2f* __restrict__ xp = reinterpret_cast<const v2f*>(X) + (size_t)b * NT;
    v2f xc = xp[0];

#pragma unroll 2
    for (int t = 0; t < NT; ++t) {
        const v2f xnext = xp[(t + 1 < NT) ? (t + 1) : (NT - 1)];

        // ---------- layer 0 ----------
        const v2f xr = wxr * xc, xz = wxz * xc, xn = wxn * xc;
        const float pr = br0 + (xr.x + xr.y) + dotW(whr0, h0a, h0b, h0c);
        const float pz = bz0 + (xz.x + xz.y) + dotW(whz0, h0a, h0b, h0c);
        const float ph = bhn0 + dotW(whn0, h0a, h0b, h0c);
        const float px = bxn0 + (xn.x + xn.y);
        const float r = sigm(pr);
        const float z = sigm(pz);
        const float n = tanhx(px + r * ph);
        my0 = n + z * (my0 - n);

        // same-wave LDS broadcast: 1 write + b128/b128/b64 reads
        h0s[j] = my0;
        h0a = *reinterpret_cast<const v4f*>(h0s);
        h0b = *reinterpret_cast<const v4f*>(h0s + 4);
        h0c = *reinterpret_cast<const v2f*>(h0s + 8);

        // ---------- layer 1 (input = h0 at this t) ----------
        const float pr1 = br1 + dotWW(wir1, h0a, h0b, h0c, whr1, h1a, h1b, h1c);
        const float pz1 = bz1 + dotWW(wiz1, h0a, h0b, h0c, whz1, h1a, h1b, h1c);
        const float px1 = bxn1 + dotW(win1, h0a, h0b, h0c);
        const float ph1 = bhn1 + dotW(whn1, h1a, h1b, h1c);
        const float r1 = sigm(pr1);
        const float z1 = sigm(pz1);
        const float n1 = tanhx(px1 + r1 * ph1);
        my1 = n1 + z1 * (my1 - n1);

        h1s[j] = my1;
        h1a = *reinterpret_cast<const v4f*>(h1s);
        h1b = *reinterpret_cast<const v4f*>(h1s + 4);
        h1c = *reinterpret_cast<const v2f*>(h1s + 8);

        xc = xnext;
    }

    // ---------- FC head ----------
    if (active && j < 2) {
        const W10 wf = loadrow(Wfc + j * NH);
        out[(size_t)b * 2 + j] = bfc[j] + dotW(wf, h1a, h1b, h1c);
    }
}

extern "C" void kernel_launch(void* const* d_in, const int* in_sizes, int n_in,
                              void* d_out, int out_size, void* d_ws, size_t ws_size,
                              hipStream_t stream) {
    const float* X    = (const float*)d_in[0];
    const float* Wih0 = (const float*)d_in[1];
    const float* Whh0 = (const float*)d_in[2];
    const float* bih0 = (const float*)d_in[3];
    const float* bhh0 = (const float*)d_in[4];
    const float* Wih1 = (const float*)d_in[5];
    const float* Whh1 = (const float*)d_in[6];
    const float* bih1 = (const float*)d_in[7];
    const float* bhh1 = (const float*)d_in[8];
    const float* Wfc  = (const float*)d_in[9];
    const float* bfc  = (const float*)d_in[10];
    float* out = (float*)d_out;

    const int grid = NB / 16;  // 512 blocks x 4 waves = 2048 waves = 2/SIMD exactly
    gru_fused<<<grid, 256, 0, stream>>>(X, Wih0, Whh0, bih0, bhh0,
                                        Wih1, Whh1, bih1, bhh1, Wfc, bfc, out);
}

// Round 5
// 547.961 us; speedup vs baseline: 1.1208x; 1.1208x over previous
//
#include <hip/hip_runtime.h>

#define NB 8192
#define NT 1024
#define NH 10
#define ROWS_PER_WAVE 4     // 10 lanes/row, lanes 40..63 idle
#define ROWS_PER_BLOCK 16   // 4 waves/block
typedef float v2f __attribute__((ext_vector_type(2)));

__device__ __forceinline__ float rcpf(float x) { return __builtin_amdgcn_rcpf(x); }
__device__ __forceinline__ float sigm(float x) { return rcpf(1.0f + __expf(-x)); }
__device__ __forceinline__ float tanhx(float x) { return 1.0f - 2.0f * rcpf(__expf(2.0f * x) + 1.0f); }
__device__ __forceinline__ float bperm(int addr, float v) {
    return __int_as_float(__builtin_amdgcn_ds_bpermute(addr, __float_as_int(v)));
}
__device__ __forceinline__ float hsum(v2f a) { return a.x + a.y; }

// waves_per_eu(2,2): we launch exactly 2 waves/SIMD (2048 waves). Without the
// max bound the allocator optimizes pressure for 8 waves/SIMD (VGPR=80 < the
// ~90 floats of weights) and re-loads/AGPR-bounces weights every timestep.
__attribute__((amdgpu_waves_per_eu(2, 2)))
__global__ __launch_bounds__(256) void gru_fused(
    const float* __restrict__ X,
    const float* __restrict__ Wih0, const float* __restrict__ Whh0,
    const float* __restrict__ bih0, const float* __restrict__ bhh0,
    const float* __restrict__ Wih1, const float* __restrict__ Whh1,
    const float* __restrict__ bih1, const float* __restrict__ bhh1,
    const float* __restrict__ Wfc,  const float* __restrict__ bfc,
    float* __restrict__ out)
{
    const int tid  = threadIdx.x;
    const int lane = tid & 63;
    const int wave = tid >> 6;
    const int g    = lane / 10;      // group in wave: 0..3 real, 4..6 idle
    const int j    = lane - g * 10;  // 0..9: this lane's hidden/gate index
    const int base = g * 10;

    const bool active = (g < ROWS_PER_WAVE);
    int b = blockIdx.x * ROWS_PER_BLOCK + wave * ROWS_PER_WAVE + (active ? g : 0);
    const bool store_ok = active && (b < NB);
    if (b >= NB) b = NB - 1;

    const int r0 = j, r1 = j + 10, r2 = j + 20;

    // ---- per-lane weights, packed as float2 (rows are 40B -> 8B aligned) ----
    v2f wxr = *reinterpret_cast<const v2f*>(Wih0 + r0 * 2);
    v2f wxz = *reinterpret_cast<const v2f*>(Wih0 + r1 * 2);
    v2f wxn = *reinterpret_cast<const v2f*>(Wih0 + r2 * 2);

    v2f whr0[5], whz0[5], whn0[5];
    v2f wir1[5], wiz1[5], win1[5];
    v2f whr1[5], whz1[5], whn1[5];
#pragma unroll
    for (int k = 0; k < 5; ++k) {
        whr0[k] = *reinterpret_cast<const v2f*>(Whh0 + r0 * NH + 2 * k);
        whz0[k] = *reinterpret_cast<const v2f*>(Whh0 + r1 * NH + 2 * k);
        whn0[k] = *reinterpret_cast<const v2f*>(Whh0 + r2 * NH + 2 * k);
        wir1[k] = *reinterpret_cast<const v2f*>(Wih1 + r0 * NH + 2 * k);
        wiz1[k] = *reinterpret_cast<const v2f*>(Wih1 + r1 * NH + 2 * k);
        win1[k] = *reinterpret_cast<const v2f*>(Wih1 + r2 * NH + 2 * k);
        whr1[k] = *reinterpret_cast<const v2f*>(Whh1 + r0 * NH + 2 * k);
        whz1[k] = *reinterpret_cast<const v2f*>(Whh1 + r1 * NH + 2 * k);
        whn1[k] = *reinterpret_cast<const v2f*>(Whh1 + r2 * NH + 2 * k);
    }
    float br0  = bih0[r0] + bhh0[r0];
    float bz0  = bih0[r1] + bhh0[r1];
    float bxn0 = bih0[r2];
    float bhn0 = bhh0[r2];
    float br1  = bih1[r0] + bhh1[r0];
    float bz1  = bih1[r1] + bhh1[r1];
    float bxn1 = bih1[r2];
    float bhn1 = bhh1[r2];

    // bpermute base byte address; +const folds into the DS offset immediate
    const int ad0 = base << 2;

    v2f h0p[5], h1p[5];
#pragma unroll
    for (int k = 0; k < 5; ++k) { h0p[k] = (v2f){0.f, 0.f}; h1p[k] = (v2f){0.f, 0.f}; }
    float my_h0 = 0.0f, my_h1 = 0.0f;

    const float2* xp = reinterpret_cast<const float2*>(X) + (size_t)b * NT;
    float2 xc = xp[0];

    for (int t = 0; t < NT; ++t) {
        const float2 xnext = xp[(t + 1 < NT) ? (t + 1) : (NT - 1)];
        const v2f xv = {xc.x, xc.y};

        // ---------- layer 0 ----------
        v2f ar = wxr * xv;
        v2f az = wxz * xv;
        v2f anx = wxn * xv;
        v2f anh = {0.f, 0.f};
#pragma unroll
        for (int k = 0; k < 5; ++k) {
            ar  += whr0[k] * h0p[k];
            az  += whz0[k] * h0p[k];
            anh += whn0[k] * h0p[k];
        }
        const float r = sigm(br0 + hsum(ar));
        const float z = sigm(bz0 + hsum(az));
        const float n = tanhx(bxn0 + hsum(anx) + r * (bhn0 + hsum(anh)));
        my_h0 = n + z * (my_h0 - n);
#pragma unroll
        for (int k = 0; k < 5; ++k) {
            h0p[k].x = bperm(ad0 + 8 * k,     my_h0);
            h0p[k].y = bperm(ad0 + 8 * k + 4, my_h0);
        }

        // ---------- layer 1 ----------
        v2f a1r = {0.f, 0.f}, a1z = {0.f, 0.f}, a1n = {0.f, 0.f}, a1h = {0.f, 0.f};
#pragma unroll
        for (int k = 0; k < 5; ++k) {
            a1r += wir1[k] * h0p[k];
            a1z += wiz1[k] * h0p[k];
            a1n += win1[k] * h0p[k];
        }
#pragma unroll
        for (int k = 0; k < 5; ++k) {
            a1r += whr1[k] * h1p[k];
            a1z += whz1[k] * h1p[k];
            a1h += whn1[k] * h1p[k];
        }
        const float r1 = sigm(br1 + hsum(a1r));
        const float z1 = sigm(bz1 + hsum(a1z));
        const float n1 = tanhx(bxn1 + hsum(a1n) + r1 * (bhn1 + hsum(a1h)));
        my_h1 = n1 + z1 * (my_h1 - n1);
#pragma unroll
        for (int k = 0; k < 5; ++k) {
            h1p[k].x = bperm(ad0 + 8 * k,     my_h1);
            h1p[k].y = bperm(ad0 + 8 * k + 4, my_h1);
        }

        xc = xnext;
    }

    // ---------- FC head ----------
    if (store_ok && j < 2) {
        float acc = bfc[j];
#pragma unroll
        for (int k = 0; k < 5; ++k)
            acc += Wfc[j * NH + 2 * k] * h1p[k].x + Wfc[j * NH + 2 * k + 1] * h1p[k].y;
        out[(size_t)b * 2 + j] = acc;
    }
}

extern "C" void kernel_launch(void* const* d_in, const int* in_sizes, int n_in,
                              void* d_out, int out_size, void* d_ws, size_t ws_size,
                              hipStream_t stream) {
    const float* X    = (const float*)d_in[0];
    const float* Wih0 = (const float*)d_in[1];
    const float* Whh0 = (const float*)d_in[2];
    const float* bih0 = (const float*)d_in[3];
    const float* bhh0 = (const float*)d_in[4];
    const float* Wih1 = (const float*)d_in[5];
    const float* Whh1 = (const float*)d_in[6];
    const float* bih1 = (const float*)d_in[7];
    const float* bhh1 = (const float*)d_in[8];
    const float* Wfc  = (const float*)d_in[9];
    const float* bfc  = (const float*)d_in[10];
    float* out = (float*)d_out;

    const int grid = NB / ROWS_PER_BLOCK;  // 512 blocks -> 2048 waves = 2/SIMD exactly
    gru_fused<<<grid, 256, 0, stream>>>(X, Wih0, Whh0, bih0, bhh0,
                                        Wih1, Whh1, bih1, bhh1, Wfc, bfc, out);
}